// Round 3
// baseline (111.177 us; speedup 1.0000x reference)
//
#include <hip/hip_runtime.h>

// Spherical harmonics (real/imag), LMAX=4, N=1e6.
// Layout (deduced R2): PLANAR — out[0 : N*25] = yr row-major (N,25),
//                      out[N*25 : 2*N*25] = yi row-major (N,25).
// Memory-bound: ~12 MB read + ~200 MB write. LDS-staged coalesced stores.
// All global stores clamped to out_size (R1 aborted on OOB; never again).

constexpr int BLOCK = 256;
constexpr int NC = 25;          // components per point per plane
constexpr int LDS_STRIDE = 26;  // gcd(26,32)=2 -> 2-way aliasing, free (m136)

__global__ __launch_bounds__(BLOCK) void sh_kernel(
    const float* __restrict__ rhat, float* __restrict__ out,
    int n, long long out_size) {
    __shared__ float lds[BLOCK * LDS_STRIDE];
    const int tid = threadIdx.x;
    const int p = blockIdx.x * BLOCK + tid;

    float re[NC], im[NC];
    #pragma unroll
    for (int j = 0; j < NC; ++j) { re[j] = 0.0f; im[j] = 0.0f; }

    if (p < n) {
        const float rx = rhat[3 * p + 0];
        const float ry = rhat[3 * p + 1];
        const float rz = rhat[3 * p + 2];

        // --- Legendre (reference's recurrence, fp32 constants) ---
        const float p00 = 0.28209479177387814f;
        const float p10 = 0.4886025119029199f * rz;
        const float p11 = -0.34549414947133544f;
        const float p20 = 1.9364916731037085f * (rz * p10 + (-0.5773502691896257f) * p00);
        const float p21 = 2.23606797749979f * rz * p11;
        const float p22 = -1.118033988749895f * p11;
        const float p30 = 1.9720265943665387f * (rz * p20 + (-0.5163977794943222f) * p10);
        const float p31 = 2.091650066335189f  * (rz * p21 + (-0.4472135954999579f) * p11);
        const float p32 = 2.6457513110645906f * rz * p22;
        const float p33 = -1.0801234497346435f * p22;
        const float p40 = 1.984313483298443f  * (rz * p30 + (-0.50709255283711f)   * p20);
        const float p41 = 2.0493901531919196f * (rz * p31 + (-0.4780914437337574f) * p21);
        const float p42 = 2.29128784747792f   * (rz * p32 + (-0.3779644730092272f) * p22);
        const float p43 = 3.0f * rz * p33;
        const float p44 = -1.0606601717798212f * p33;

        // --- (rx + i ry)^m ---
        const float c1r = rx, c1i = ry;
        const float c2r = c1r * rx - c1i * ry, c2i = c1r * ry + c1i * rx;
        const float c3r = c2r * rx - c2i * ry, c3i = c2r * ry + c2i * rx;
        const float c4r = c3r * rx - c3i * ry, c4i = c3r * ry + c3i * rx;

        const float y11r = c1r * p11, y11i = c1i * p11;
        const float y21r = c1r * p21, y21i = c1i * p21;
        const float y22r = c2r * p22, y22i = c2i * p22;
        const float y31r = c1r * p31, y31i = c1i * p31;
        const float y32r = c2r * p32, y32i = c2i * p32;
        const float y33r = c3r * p33, y33i = c3i * p33;
        const float y41r = c1r * p41, y41i = c1i * p41;
        const float y42r = c2r * p42, y42i = c2i * p42;
        const float y43r = c3r * p43, y43i = c3i * p43;
        const float y44r = c4r * p44, y44i = c4i * p44;

        // order: l=0..4, m=-l..l; m<0: ph=(-1)^|m|, (r*ph, -i*ph)
        re[0]  = p00;                       // (0,0)
        re[1]  = -y11r;  im[1]  = y11i;     // (1,-1)
        re[2]  = p10;                       // (1,0)
        re[3]  = y11r;   im[3]  = y11i;     // (1,1)
        re[4]  = y22r;   im[4]  = -y22i;    // (2,-2)
        re[5]  = -y21r;  im[5]  = y21i;     // (2,-1)
        re[6]  = p20;                       // (2,0)
        re[7]  = y21r;   im[7]  = y21i;     // (2,1)
        re[8]  = y22r;   im[8]  = y22i;     // (2,2)
        re[9]  = -y33r;  im[9]  = y33i;     // (3,-3)
        re[10] = y32r;   im[10] = -y32i;    // (3,-2)
        re[11] = -y31r;  im[11] = y31i;     // (3,-1)
        re[12] = p30;                       // (3,0)
        re[13] = y31r;   im[13] = y31i;     // (3,1)
        re[14] = y32r;   im[14] = y32i;     // (3,2)
        re[15] = y33r;   im[15] = y33i;     // (3,3)
        re[16] = y44r;   im[16] = -y44i;    // (4,-4)
        re[17] = -y43r;  im[17] = y43i;     // (4,-3)
        re[18] = y42r;   im[18] = -y42i;    // (4,-2)
        re[19] = -y41r;  im[19] = y41i;     // (4,-1)
        re[20] = p40;                       // (4,0)
        re[21] = y41r;   im[21] = y41i;     // (4,1)
        re[22] = y42r;   im[22] = y42i;     // (4,2)
        re[23] = y43r;   im[23] = y43i;     // (4,3)
        re[24] = y44r;   im[24] = y44i;     // (4,4)
    }

    const long long plane = (long long)n * NC;          // 25e6
    const long long base = (long long)blockIdx.x * (BLOCK * NC);
    float* row = &lds[tid * LDS_STRIDE];

    // ---- plane 0: real ----
    #pragma unroll
    for (int j = 0; j < NC; ++j) row[j] = re[j];
    __syncthreads();
    #pragma unroll
    for (int k = 0; k < NC; ++k) {
        const int idx = k * BLOCK + tid;               // coalesced
        const long long g = base + idx;
        if (g < plane && g < out_size) {
            const int pt = idx / NC, wi = idx - pt * NC;
            out[g] = lds[pt * LDS_STRIDE + wi];
        }
    }
    __syncthreads();

    // ---- plane 1: imag ----
    #pragma unroll
    for (int j = 0; j < NC; ++j) row[j] = im[j];
    __syncthreads();
    #pragma unroll
    for (int k = 0; k < NC; ++k) {
        const int idx = k * BLOCK + tid;
        const long long g = plane + base + idx;
        if (base + idx < plane && g < out_size) {
            const int pt = idx / NC, wi = idx - pt * NC;
            out[g] = lds[pt * LDS_STRIDE + wi];
        }
    }
}

extern "C" void kernel_launch(void* const* d_in, const int* in_sizes, int n_in,
                              void* d_out, int out_size, void* d_ws, size_t ws_size,
                              hipStream_t stream) {
    const float* rhat = (const float*)d_in[0];
    float* out = (float*)d_out;
    const int n = in_sizes[0] / 3;
    const int grid = (n + BLOCK - 1) / BLOCK;
    sh_kernel<<<grid, BLOCK, 0, stream>>>(rhat, out, n, (long long)out_size);
}

// Round 8
// 110.411 us; speedup vs baseline: 1.0069x; 1.0069x over previous
//
#include <hip/hip_runtime.h>

// Spherical harmonics (real/imag), LMAX=4, N=1e6.
// Layout (verified R3 PASS): PLANAR — out[0:N*25]=yr (N,25), out[N*25:]=yi.
//
// RE-ANCHOR ROUND: this is the R3 kernel byte-identical (only comments
// changed). History: R3 passed the FULL pipeline (validate + graph capture +
// timing + rocprof) at 111 us. Every structural variant since — R4 (float4
// drain, wrong values), R5 (float4 memcpy drain, abort), R6 (pair-merged
// float2 drain, abort), R7 (no-LDS register-direct float2, abort) — failed,
// despite exhaustive bounds audits proving all accesses in-bounds. Aborts are
// not explainable by kernel semantics; re-running the proven kernel verbatim
// distinguishes environment flake from content-correlated failure.
//
// Perf note: 111 us = 1.9 TB/s effective, scalar-store (4 B/lane) regime.
// The fill kernel shows 6.6 TB/s with dwordx4 on this buffer, but every
// wide-store restructure has died; treat ~111 us as this structure's anchor.

constexpr int BLOCK = 256;
constexpr int NC = 25;          // components per point per plane
constexpr int LDS_STRIDE = 26;  // gcd(26,32)=2 -> 2-way aliasing, free (m136)

__global__ __launch_bounds__(BLOCK) void sh_kernel(
    const float* __restrict__ rhat, float* __restrict__ out,
    int n, long long out_size) {
    __shared__ float lds[BLOCK * LDS_STRIDE];
    const int tid = threadIdx.x;
    const int p = blockIdx.x * BLOCK + tid;

    float re[NC], im[NC];
    #pragma unroll
    for (int j = 0; j < NC; ++j) { re[j] = 0.0f; im[j] = 0.0f; }

    if (p < n) {
        const float rx = rhat[3 * p + 0];
        const float ry = rhat[3 * p + 1];
        const float rz = rhat[3 * p + 2];

        // --- Legendre (reference's recurrence, fp32 constants) ---
        const float p00 = 0.28209479177387814f;
        const float p10 = 0.4886025119029199f * rz;
        const float p11 = -0.34549414947133544f;
        const float p20 = 1.9364916731037085f * (rz * p10 + (-0.5773502691896257f) * p00);
        const float p21 = 2.23606797749979f * rz * p11;
        const float p22 = -1.118033988749895f * p11;
        const float p30 = 1.9720265943665387f * (rz * p20 + (-0.5163977794943222f) * p10);
        const float p31 = 2.091650066335189f  * (rz * p21 + (-0.4472135954999579f) * p11);
        const float p32 = 2.6457513110645906f * rz * p22;
        const float p33 = -1.0801234497346435f * p22;
        const float p40 = 1.984313483298443f  * (rz * p30 + (-0.50709255283711f)   * p20);
        const float p41 = 2.0493901531919196f * (rz * p31 + (-0.4780914437337574f) * p21);
        const float p42 = 2.29128784747792f   * (rz * p32 + (-0.3779644730092272f) * p22);
        const float p43 = 3.0f * rz * p33;
        const float p44 = -1.0606601717798212f * p33;

        // --- (rx + i ry)^m ---
        const float c1r = rx, c1i = ry;
        const float c2r = c1r * rx - c1i * ry, c2i = c1r * ry + c1i * rx;
        const float c3r = c2r * rx - c2i * ry, c3i = c2r * ry + c2i * rx;
        const float c4r = c3r * rx - c3i * ry, c4i = c3r * ry + c3i * rx;

        const float y11r = c1r * p11, y11i = c1i * p11;
        const float y21r = c1r * p21, y21i = c1i * p21;
        const float y22r = c2r * p22, y22i = c2i * p22;
        const float y31r = c1r * p31, y31i = c1i * p31;
        const float y32r = c2r * p32, y32i = c2i * p32;
        const float y33r = c3r * p33, y33i = c3i * p33;
        const float y41r = c1r * p41, y41i = c1i * p41;
        const float y42r = c2r * p42, y42i = c2i * p42;
        const float y43r = c3r * p43, y43i = c3i * p43;
        const float y44r = c4r * p44, y44i = c4i * p44;

        // order: l=0..4, m=-l..l; m<0: ph=(-1)^|m|, (r*ph, -i*ph)
        re[0]  = p00;                       // (0,0)
        re[1]  = -y11r;  im[1]  = y11i;     // (1,-1)
        re[2]  = p10;                       // (1,0)
        re[3]  = y11r;   im[3]  = y11i;     // (1,1)
        re[4]  = y22r;   im[4]  = -y22i;    // (2,-2)
        re[5]  = -y21r;  im[5]  = y21i;     // (2,-1)
        re[6]  = p20;                       // (2,0)
        re[7]  = y21r;   im[7]  = y21i;     // (2,1)
        re[8]  = y22r;   im[8]  = y22i;     // (2,2)
        re[9]  = -y33r;  im[9]  = y33i;     // (3,-3)
        re[10] = y32r;   im[10] = -y32i;    // (3,-2)
        re[11] = -y31r;  im[11] = y31i;     // (3,-1)
        re[12] = p30;                       // (3,0)
        re[13] = y31r;   im[13] = y31i;     // (3,1)
        re[14] = y32r;   im[14] = y32i;     // (3,2)
        re[15] = y33r;   im[15] = y33i;     // (3,3)
        re[16] = y44r;   im[16] = -y44i;    // (4,-4)
        re[17] = -y43r;  im[17] = y43i;     // (4,-3)
        re[18] = y42r;   im[18] = -y42i;    // (4,-2)
        re[19] = -y41r;  im[19] = y41i;     // (4,-1)
        re[20] = p40;                       // (4,0)
        re[21] = y41r;   im[21] = y41i;     // (4,1)
        re[22] = y42r;   im[22] = y42i;     // (4,2)
        re[23] = y43r;   im[23] = y43i;     // (4,3)
        re[24] = y44r;   im[24] = y44i;     // (4,4)
    }

    const long long plane = (long long)n * NC;          // 25e6
    const long long base = (long long)blockIdx.x * (BLOCK * NC);
    float* row = &lds[tid * LDS_STRIDE];

    // ---- plane 0: real ----
    #pragma unroll
    for (int j = 0; j < NC; ++j) row[j] = re[j];
    __syncthreads();
    #pragma unroll
    for (int k = 0; k < NC; ++k) {
        const int idx = k * BLOCK + tid;               // coalesced
        const long long g = base + idx;
        if (g < plane && g < out_size) {
            const int pt = idx / NC, wi = idx - pt * NC;
            out[g] = lds[pt * LDS_STRIDE + wi];
        }
    }
    __syncthreads();

    // ---- plane 1: imag ----
    #pragma unroll
    for (int j = 0; j < NC; ++j) row[j] = im[j];
    __syncthreads();
    #pragma unroll
    for (int k = 0; k < NC; ++k) {
        const int idx = k * BLOCK + tid;
        const long long g = plane + base + idx;
        if (base + idx < plane && g < out_size) {
            const int pt = idx / NC, wi = idx - pt * NC;
            out[g] = lds[pt * LDS_STRIDE + wi];
        }
    }
}

extern "C" void kernel_launch(void* const* d_in, const int* in_sizes, int n_in,
                              void* d_out, int out_size, void* d_ws, size_t ws_size,
                              hipStream_t stream) {
    const float* rhat = (const float*)d_in[0];
    float* out = (float*)d_out;
    const int n = in_sizes[0] / 3;
    const int grid = (n + BLOCK - 1) / BLOCK;
    sh_kernel<<<grid, BLOCK, 0, stream>>>(rhat, out, n, (long long)out_size);
}